// Round 4
// baseline (2075.473 us; speedup 1.0000x reference)
//
#include <hip/hip_runtime.h>
#include <hip/hip_bf16.h>
#include <cstdint>

// B=2, T=2048, HID=1024, H=16, DK=DV=64, K(conv)=4. ALL inputs/outputs fp32
// (per reference dtypes). GEMMs cast fp32->bf16 at LDS staging, fp32 MFMA acc.
// Intermediates bf16 planes in d_ws: 4 x 8 MB = 32 MB peak.
// Diagnostics: ws too small -> d_out=1000.0; inputs-look-bf16 -> d_out=100.0.

using bf16 = __hip_bfloat16;

typedef __bf16 bf16x8 __attribute__((ext_vector_type(8)));
typedef float f32x4 __attribute__((ext_vector_type(4)));

__device__ __forceinline__ __bf16 cvt_bf16(float f) {
  __hip_bfloat16 h = (__hip_bfloat16)f;
  return *reinterpret_cast<__bf16*>(&h);
}

// C = A * Bt^T. A: MxK (bf16 plane if A_IS_BF16 else fp32), Bt: NxK fp32.
// MODE 2: raw -> bf16 Cb; MODE 3: sigmoid(acc+bias) -> bf16 Cb; MODE 4: raw -> fp32 Cf.
template <int MODE, bool A_IS_BF16>
__global__ __launch_bounds__(256) void gemm_bt(
    const void* __restrict__ Av, const float* __restrict__ Bt,
    const float* __restrict__ bias, float* __restrict__ Cf, bf16* __restrict__ Cb,
    int M, int N, int K)
{
  __shared__ __align__(16) __bf16 As[128 * 32];
  __shared__ __align__(16) __bf16 Bs[128 * 32];

  const int tid  = threadIdx.x;
  const int lane = tid & 63;
  const int wave = tid >> 6;
  const int tile_m = blockIdx.y * 128;
  const int tile_n = blockIdx.x * 128;
  const int wm = (wave >> 1) * 64;
  const int wn = (wave & 1) * 64;

  const int srow = lane >> 2;         // staging row within 16-row chunk
  const int scol = (lane & 3) * 8;    // staging col offset (8 elements)

  f32x4 acc[4][4];
#pragma unroll
  for (int i = 0; i < 4; ++i)
#pragma unroll
    for (int j = 0; j < 4; ++j) acc[i][j] = {0.f, 0.f, 0.f, 0.f};

  for (int k0 = 0; k0 < K; k0 += 32) {
    bf16x8 av[2], bv[2];
#pragma unroll
    for (int s = 0; s < 2; ++s) {
      int arow = tile_m + s * 64 + wave * 16 + srow;
      if (A_IS_BF16) {
        av[s] = *(const bf16x8*)((const __bf16*)Av + (size_t)arow * K + k0 + scol);
      } else {
        const float* ap = (const float*)Av + (size_t)arow * K + k0 + scol;
        float4 f0 = *(const float4*)ap;
        float4 f1 = *(const float4*)(ap + 4);
        bf16x8 t;
        t[0] = cvt_bf16(f0.x); t[1] = cvt_bf16(f0.y); t[2] = cvt_bf16(f0.z); t[3] = cvt_bf16(f0.w);
        t[4] = cvt_bf16(f1.x); t[5] = cvt_bf16(f1.y); t[6] = cvt_bf16(f1.z); t[7] = cvt_bf16(f1.w);
        av[s] = t;
      }
      int brow = tile_n + s * 64 + wave * 16 + srow;
      const float* bp = Bt + (size_t)brow * K + k0 + scol;
      float4 g0 = *(const float4*)bp;
      float4 g1 = *(const float4*)(bp + 4);
      bf16x8 u;
      u[0] = cvt_bf16(g0.x); u[1] = cvt_bf16(g0.y); u[2] = cvt_bf16(g0.z); u[3] = cvt_bf16(g0.w);
      u[4] = cvt_bf16(g1.x); u[5] = cvt_bf16(g1.y); u[6] = cvt_bf16(g1.z); u[7] = cvt_bf16(g1.w);
      bv[s] = u;
    }
    __syncthreads();   // prior iteration's LDS readers done
#pragma unroll
    for (int s = 0; s < 2; ++s) {
      *(bf16x8*)&As[(s * 64 + wave * 16 + srow) * 32 + scol] = av[s];
      *(bf16x8*)&Bs[(s * 64 + wave * 16 + srow) * 32 + scol] = bv[s];
    }
    __syncthreads();   // staging visible

    bf16x8 af[4], bfr[4];
#pragma unroll
    for (int i = 0; i < 4; ++i)
      af[i] = *(const bf16x8*)&As[(wm + i * 16 + (lane & 15)) * 32 + (lane >> 4) * 8];
#pragma unroll
    for (int j = 0; j < 4; ++j)
      bfr[j] = *(const bf16x8*)&Bs[(wn + j * 16 + (lane & 15)) * 32 + (lane >> 4) * 8];

#pragma unroll
    for (int i = 0; i < 4; ++i)
#pragma unroll
      for (int j = 0; j < 4; ++j)
        acc[i][j] = __builtin_amdgcn_mfma_f32_16x16x32_bf16(af[i], bfr[j], acc[i][j], 0, 0, 0);
  }

  // C/D layout (m89-verified): col = lane&15, row = (lane>>4)*4 + reg
#pragma unroll
  for (int i = 0; i < 4; ++i) {
#pragma unroll
    for (int j = 0; j < 4; ++j) {
#pragma unroll
      for (int r = 0; r < 4; ++r) {
        int gm = tile_m + wm + i * 16 + (lane >> 4) * 4 + r;
        int gn = tile_n + wn + j * 16 + (lane & 15);
        float val = acc[i][j][r];
        if (MODE == 3) {
          float bv2 = bias ? bias[gn] : 0.f;
          val = 1.f / (1.f + __expf(-(val + bv2)));
        }
        if (MODE == 4) Cf[(size_t)gm * N + gn] = val;
        else           Cb[(size_t)gm * N + gn] = (bf16)val;
      }
    }
  }
}

// causal depthwise conv K=4 + bias + SiLU (+scale). z: [B*T,1024] bf16 plane.
__global__ __launch_bounds__(256) void conv_silu_kernel(
    const bf16* __restrict__ z, const float* __restrict__ w,
    const float* __restrict__ bias, bf16* __restrict__ out, float scale)
{
  int idx = blockIdx.x * 256 + threadIdx.x;   // 4096*1024 total
  int c = idx & 1023;
  int m = idx >> 10;
  int t = m & 2047;                            // T = 2048
  float w0 = w[c * 4 + 0], w1 = w[c * 4 + 1], w2 = w[c * 4 + 2], w3 = w[c * 4 + 3];
  float acc = bias[c] + (float)z[idx] * w3;    // tap i multiplies z[t-3+i]
  if (t >= 1) acc += (float)z[idx - 1024] * w2;
  if (t >= 2) acc += (float)z[idx - 2048] * w1;
  if (t >= 3) acc += (float)z[idx - 3072] * w0;
  float s = acc / (1.f + __expf(-acc));        // SiLU
  out[idx] = (bf16)(s * scale);
}

// delta-rule scan: 1 block per (b,h); thread (r=tid>>2, c0=(tid&3)*16) holds
// S[r][c0..c0+15] fp32. Beta computed in-kernel from fp32 x/Wb. o MAY alias v
// (slot t written only after slot t+1 staged; barrier orders across threads).
__global__ __launch_bounds__(256) void scan_kernel(
    const bf16* __restrict__ q, const bf16* __restrict__ k,
    const bf16* v, const bf16* __restrict__ a,
    const float* __restrict__ x, const float* __restrict__ Wb,
    const float* __restrict__ bb, bf16* o)
{
  const int bh = blockIdx.x;
  const int b = bh >> 4, h = bh & 15;
  const int tid = threadIdx.x;
  const int lane = tid & 63;
  const int seg = tid >> 6;
  const int r = tid >> 2;
  const int c0 = (tid & 3) * 16;

  __shared__ float sbeta[2048];
  __shared__ __align__(16) float sbuf[2][256]; // q[0,64) k[64,128) v[128,192) a[192,256)

  // beta pre-pass: beta[t] = sigmoid(x[b,t,:] . Wb[h,:] + bb[h])
  {
    const float* wbh = Wb + (size_t)h * 1024;
    float bbh = bb[h];
    for (int t = tid; t < 2048; t += 256) {
      const float* xp = x + ((size_t)b * 2048 + t) * 1024;
      float dot = bbh;
      for (int c = 0; c < 1024; c += 4) {
        float4 xv = *(const float4*)(xp + c);
        float4 wv = *(const float4*)(wbh + c);
        dot += xv.x * wv.x + xv.y * wv.y + xv.z * wv.z + xv.w * wv.w;
      }
      sbeta[t] = 1.f / (1.f + __expf(-dot));
    }
  }

  const size_t base = (size_t)b * 2048 * 1024 + h * 64;

  float S[16];
#pragma unroll
  for (int j = 0; j < 16; ++j) S[j] = 0.f;

  {  // stage t=0
    float* nxt = sbuf[0];
    size_t off = base + lane;
    if      (seg == 0) nxt[lane]       = (float)q[off];
    else if (seg == 1) nxt[64 + lane]  = (float)k[off];
    else if (seg == 2) nxt[128 + lane] = (float)v[off];
    else               nxt[192 + lane] = (float)a[off];
  }

  for (int t = 0; t < 2048; ++t) {
    __syncthreads();
    const float* cur = sbuf[t & 1];
    float kk[16], qq[16];
#pragma unroll
    for (int j = 0; j < 16; j += 4) *(float4*)&kk[j] = *(const float4*)&cur[64 + c0 + j];
#pragma unroll
    for (int j = 0; j < 16; j += 4) *(float4*)&qq[j] = *(const float4*)&cur[c0 + j];
    float vr = cur[128 + r];
    float ar = cur[192 + r];
    float bt = sbeta[t];

    if (t + 1 < 2048) {  // stage t+1 (overlaps compute)
      float* nxt = sbuf[(t + 1) & 1];
      size_t off = base + (size_t)(t + 1) * 1024 + lane;
      if      (seg == 0) nxt[lane]       = (float)q[off];
      else if (seg == 1) nxt[64 + lane]  = (float)k[off];
      else if (seg == 2) nxt[128 + lane] = (float)v[off];
      else               nxt[192 + lane] = (float)a[off];
    }

    float dot = 0.f;
#pragma unroll
    for (int j = 0; j < 16; ++j) dot += S[j] * kk[j];
    dot += __shfl_xor(dot, 1);
    dot += __shfl_xor(dot, 2);
    float cc = bt * (dot - vr);          // beta * err[r]
    float od = 0.f;
#pragma unroll
    for (int j = 0; j < 16; ++j) {
      S[j] = ar * S[j] - cc * kk[j];
      od += S[j] * qq[j];
    }
    od += __shfl_xor(od, 1);
    od += __shfl_xor(od, 2);
    if ((tid & 3) == 0) o[base + (size_t)t * 1024 + r] = (bf16)od;
  }
}

// LayerNorm over DV=64 per (b,t,h) row, *ln_w+ln_b, *gate -> bf16
__global__ __launch_bounds__(256) void ln_gate_kernel(
    const bf16* __restrict__ o, const bf16* __restrict__ g,
    const float* __restrict__ lnw, const float* __restrict__ lnb,
    bf16* __restrict__ out)
{
  int row = blockIdx.x * 4 + (threadIdx.x >> 6);
  int lane = threadIdx.x & 63;
  size_t idx = (size_t)row * 64 + lane;
  float xv = (float)o[idx];
  float mu = xv;
#pragma unroll
  for (int s = 1; s < 64; s <<= 1) mu += __shfl_xor(mu, s);
  mu *= (1.f / 64.f);
  float d = xv - mu;
  float vv = d * d;
#pragma unroll
  for (int s = 1; s < 64; s <<= 1) vv += __shfl_xor(vv, s);
  vv *= (1.f / 64.f);
  float y = d * rsqrtf(vv + 1e-5f) * lnw[lane] + lnb[lane];
  y *= (float)g[idx];
  out[idx] = (bf16)y;
}

// dtype sniffer: even bf16-slots of fp32 data are uniform bit-noise (~47%
// extreme exponents); of true bf16 N(0,1) data they are tame (~0%).
__global__ void sniff_kernel(const unsigned short* xs, int* flag) {
  __shared__ int cnt;
  if (threadIdx.x == 0) cnt = 0;
  __syncthreads();
  int c = 0;
  for (int i = threadIdx.x; i < 1024; i += 256) {
    unsigned short u = xs[2 * i];
    int e = (u >> 7) & 0xFF;
    if (e >= 135) c++;   // |val| >= 256 or inf/nan
  }
  atomicAdd(&cnt, c);
  __syncthreads();
  if (threadIdx.x == 0) *flag = (cnt >= 64) ? 1 : 0;   // 1 = fp32 confirmed
}

__global__ void fill_kernel(float* out, float val) {
  out[(size_t)blockIdx.x * 256 + threadIdx.x] = val;
}
__global__ void sentinel_kernel(const int* flag, float* out) {
  if (*flag == 0) out[(size_t)blockIdx.x * 256 + threadIdx.x] = 100.0f;
}

extern "C" void kernel_launch(void* const* d_in, const int* in_sizes, int n_in,
                              void* d_out, int out_size, void* d_ws, size_t ws_size,
                              hipStream_t stream)
{
  const float* x   = (const float*)d_in[0];
  const float* Wq  = (const float*)d_in[1];
  const float* Wk  = (const float*)d_in[2];
  const float* Wv  = (const float*)d_in[3];
  const float* Wa  = (const float*)d_in[4];
  const float* ba  = (const float*)d_in[5];
  const float* Wb  = (const float*)d_in[6];
  const float* bb  = (const float*)d_in[7];
  const float* Wg  = (const float*)d_in[8];
  const float* Wo  = (const float*)d_in[9];
  const float* qcw = (const float*)d_in[10];
  const float* qcb = (const float*)d_in[11];
  const float* kcw = (const float*)d_in[12];
  const float* kcb = (const float*)d_in[13];
  const float* vcw = (const float*)d_in[14];
  const float* vcb = (const float*)d_in[15];
  const float* lnw = (const float*)d_in[16];
  const float* lnb = (const float*)d_in[17];

  const int M = 4096, HID = 1024;
  const size_t PLANE = (size_t)M * HID;             // elements
  const size_t PB = PLANE * sizeof(bf16);           // 8 MB bf16 plane
  const size_t NEED = 4 * PB + 256;

  float* outf = (float*)d_out;
  dim3 blk(256);

  if (ws_size < NEED) {                             // diagnostic: scratch too small
    fill_kernel<<<(int)(PLANE / 256), blk, 0, stream>>>(outf, 1000.0f);
    return;
  }

  char* ws = (char*)d_ws;
  bf16* P  = (bf16*)(ws);            // z-plane x3, then a-gate
  bf16* qb = (bf16*)(ws + PB);       // q, then g-gate
  bf16* kb = (bf16*)(ws + 2 * PB);   // k, then normalized*gated o
  bf16* vb = (bf16*)(ws + 3 * PB);   // v, then scan output (in-place overlay)
  int* flag = (int*)(ws + 4 * PB);

  sniff_kernel<<<1, blk, 0, stream>>>((const unsigned short*)x, flag);

  dim3 g8(8, 32);
  int nconv = (int)(PLANE / 256);

  gemm_bt<2, false><<<g8, blk, 0, stream>>>(x, Wq, nullptr, nullptr, P, M, HID, HID);
  conv_silu_kernel<<<nconv, blk, 0, stream>>>(P, qcw, qcb, qb, 1.f);

  gemm_bt<2, false><<<g8, blk, 0, stream>>>(x, Wk, nullptr, nullptr, P, M, HID, HID);
  conv_silu_kernel<<<nconv, blk, 0, stream>>>(P, kcw, kcb, kb, 0.125f);  // * DK^-0.5

  gemm_bt<2, false><<<g8, blk, 0, stream>>>(x, Wv, nullptr, nullptr, P, M, HID, HID);
  conv_silu_kernel<<<nconv, blk, 0, stream>>>(P, vcw, vcb, vb, 1.f);

  gemm_bt<3, false><<<g8, blk, 0, stream>>>(x, Wa, ba, nullptr, P, M, HID, HID);

  scan_kernel<<<32, blk, 0, stream>>>(qb, kb, vb, P, x, Wb, bb, vb);

  gemm_bt<3, false><<<g8, blk, 0, stream>>>(x, Wg, nullptr, nullptr, qb, M, HID, HID);

  ln_gate_kernel<<<M * 16 / 4, blk, 0, stream>>>(vb, qb, lnw, lnb, kb);

  gemm_bt<4, true><<<g8, blk, 0, stream>>>(kb, Wo, nullptr, outf, nullptr, M, HID, HID);

  sentinel_kernel<<<(int)(PLANE / 256), blk, 0, stream>>>(flag, outf);  // bf16-detected diag
}

// Round 5
// 1164.653 us; speedup vs baseline: 1.7821x; 1.7821x over previous
//
#include <hip/hip_runtime.h>
#include <hip/hip_bf16.h>
#include <cstdint>

// B=2, T=2048, HID=1024, H=16, DK=DV=64, K(conv)=4. fp32 in/out.
// ws: 4 bf16 planes (32 MB). d_out doubles as scratch: betab fp32 [0,256K),
// xb bf16 plane at [8M,16M) -- both consumed before the final GEMM writes d_out.

using bf16 = __hip_bfloat16;
typedef __bf16 bf16x8 __attribute__((ext_vector_type(8)));
typedef __bf16 bf16x4v __attribute__((ext_vector_type(4)));
typedef float f32x4 __attribute__((ext_vector_type(4)));

__device__ __forceinline__ __bf16 cvt_bf16(float f) {
  __hip_bfloat16 h = (__hip_bfloat16)f;
  return *reinterpret_cast<__bf16*>(&h);
}
__device__ __forceinline__ void async_copy16(const void* g, void* l) {
  __builtin_amdgcn_global_load_lds((const __attribute__((address_space(1))) void*)g,
                                   (__attribute__((address_space(3))) void*)l,
                                   16, 0, 0);
}

// fp32 -> bf16 plane (4M elements)
__global__ __launch_bounds__(256) void cvt_plane_kernel(
    const float* __restrict__ in, bf16* __restrict__ out)
{
  size_t i = ((size_t)blockIdx.x * 256 + threadIdx.x) * 4;
  float4 f = *(const float4*)(in + i);
  bf16x4v t;
  t[0] = cvt_bf16(f.x); t[1] = cvt_bf16(f.y); t[2] = cvt_bf16(f.z); t[3] = cvt_bf16(f.w);
  *(bf16x4v*)((__bf16*)out + i) = t;
}

// C = A * Bt^T. A: MxK bf16 (async global->LDS, m97 pattern); Bt: NxK fp32 (cvt at staging).
// MODE 1: sigmoid(acc+bias)->fp32 Cf; 2: raw->bf16 Cb; 3: sigmoid(acc+bias)->bf16 Cb; 4: raw->fp32 Cf
template <int MODE>
__global__ __launch_bounds__(256) void gemm_bt(
    const bf16* __restrict__ A, const float* __restrict__ Bt,
    const float* __restrict__ bias, float* __restrict__ Cf, bf16* __restrict__ Cb,
    int M, int N, int K)
{
  __shared__ __align__(16) __bf16 As[128 * 32];
  __shared__ __align__(16) __bf16 Bs[128 * 32];

  const int tid  = threadIdx.x;
  const int lane = tid & 63;
  const int wave = tid >> 6;
  const int tile_m = blockIdx.y * 128;
  const int tile_n = blockIdx.x * 128;
  const int wm = (wave >> 1) * 64;
  const int wn = (wave & 1) * 64;

  const int srow = lane >> 2;         // staging row within 16-row chunk
  const int scol = (lane & 3) * 8;    // staging col offset (8 elements = 16B bf16)

  f32x4 acc[4][4];
#pragma unroll
  for (int i = 0; i < 4; ++i)
#pragma unroll
    for (int j = 0; j < 4; ++j) acc[i][j] = {0.f, 0.f, 0.f, 0.f};

  for (int k0 = 0; k0 < K; k0 += 32) {
    // B: fp32 global -> regs (issued early)
    float4 b0[2], b1[2];
#pragma unroll
    for (int s = 0; s < 2; ++s) {
      int brow = tile_n + s * 64 + wave * 16 + srow;
      if (brow > N - 1) brow = N - 1;             // clamp (beta GEMM: N=16)
      const float* bp = Bt + (size_t)brow * K + k0 + scol;
      b0[s] = *(const float4*)bp;
      b1[s] = *(const float4*)(bp + 4);
    }
    __syncthreads();   // prior iteration's LDS readers done
#pragma unroll
    for (int s = 0; s < 2; ++s) {
      // A: async 16B direct-to-LDS. LDS addr = wave-uniform + lane*16 (verified layout)
      int arow = tile_m + s * 64 + wave * 16 + srow;
      async_copy16((const __bf16*)A + (size_t)arow * K + k0 + scol,
                   &As[(s * 64 + wave * 16 + srow) * 32 + scol]);
      bf16x8 u;
      u[0] = cvt_bf16(b0[s].x); u[1] = cvt_bf16(b0[s].y);
      u[2] = cvt_bf16(b0[s].z); u[3] = cvt_bf16(b0[s].w);
      u[4] = cvt_bf16(b1[s].x); u[5] = cvt_bf16(b1[s].y);
      u[6] = cvt_bf16(b1[s].z); u[7] = cvt_bf16(b1[s].w);
      *(bf16x8*)&Bs[(s * 64 + wave * 16 + srow) * 32 + scol] = u;
    }
    __syncthreads();   // drains vmcnt (async LDS writes) + lgkm

    bf16x8 af[4], bfr[4];
#pragma unroll
    for (int i = 0; i < 4; ++i)
      af[i] = *(const bf16x8*)&As[(wm + i * 16 + (lane & 15)) * 32 + (lane >> 4) * 8];
#pragma unroll
    for (int j = 0; j < 4; ++j)
      bfr[j] = *(const bf16x8*)&Bs[(wn + j * 16 + (lane & 15)) * 32 + (lane >> 4) * 8];

#pragma unroll
    for (int i = 0; i < 4; ++i)
#pragma unroll
      for (int j = 0; j < 4; ++j)
        acc[i][j] = __builtin_amdgcn_mfma_f32_16x16x32_bf16(af[i], bfr[j], acc[i][j], 0, 0, 0);
  }

  // C/D layout (m89-verified): col = lane&15, row = (lane>>4)*4 + reg
#pragma unroll
  for (int i = 0; i < 4; ++i) {
#pragma unroll
    for (int j = 0; j < 4; ++j) {
#pragma unroll
      for (int r = 0; r < 4; ++r) {
        int gm = tile_m + wm + i * 16 + (lane >> 4) * 4 + r;
        int gn = tile_n + wn + j * 16 + (lane & 15);
        if (gn < N) {
          float val = acc[i][j][r];
          if (MODE == 1 || MODE == 3) {
            float bv = bias ? bias[gn] : 0.f;
            val = 1.f / (1.f + __expf(-(val + bv)));
          }
          if (MODE == 1 || MODE == 4) Cf[(size_t)gm * N + gn] = val;
          else                        Cb[(size_t)gm * N + gn] = (bf16)val;
        }
      }
    }
  }
}

// causal depthwise conv K=4 + bias + SiLU (+scale). z: [B*T,1024] bf16 plane.
__global__ __launch_bounds__(256) void conv_silu_kernel(
    const bf16* __restrict__ z, const float* __restrict__ w,
    const float* __restrict__ bias, bf16* __restrict__ out, float scale)
{
  int idx = blockIdx.x * 256 + threadIdx.x;   // 4096*1024 total
  int c = idx & 1023;
  int m = idx >> 10;
  int t = m & 2047;                            // T = 2048
  float w0 = w[c * 4 + 0], w1 = w[c * 4 + 1], w2 = w[c * 4 + 2], w3 = w[c * 4 + 3];
  float acc = bias[c] + (float)z[idx] * w3;    // tap i multiplies z[t-3+i]
  if (t >= 1) acc += (float)z[idx - 1024] * w2;
  if (t >= 2) acc += (float)z[idx - 2048] * w1;
  if (t >= 3) acc += (float)z[idx - 3072] * w0;
  float s = acc / (1.f + __expf(-acc));        // SiLU
  out[idx] = (bf16)(s * scale);
}

// delta-rule scan, chunked: 1 block/(b,h); 256 thr; thread (r=tid>>2, c0=(tid&3)*16)
// holds S[r][c0..c0+15] fp32. 16 steps staged per chunk, double-buffered LDS:
// 1 barrier / 16 steps, global latency amortized. o aliases v (row t written in
// chunk c; v rows of chunk c+1 are strictly future rows -> race-free).
__global__ __launch_bounds__(256) void scan_kernel(
    const bf16* __restrict__ q, const bf16* __restrict__ k,
    const bf16* v, const bf16* __restrict__ a,
    const float* __restrict__ betab, bf16* o)
{
  const int bh = blockIdx.x;
  const int b = bh >> 4, h = bh & 15;
  const int tid = threadIdx.x;
  const int lane = tid & 63;
  const int seg = tid >> 6;
  const int r = tid >> 2;
  const int c0 = (tid & 3) * 16;

  __shared__ __align__(16) float sp[4][2][16][64];   // 32 KB: plane/buf/step/col
  __shared__ float sbeta[2048];                      // 8 KB

  for (int t = tid; t < 2048; t += 256)
    sbeta[t] = betab[((size_t)b * 2048 + t) * 16 + h];

  const size_t base = (size_t)b * 2048 * 1024 + h * 64;
  const bf16* pl = (seg == 0) ? q : (seg == 1) ? k : (seg == 2) ? v : a;
  const int col8 = (lane & 7) * 8;
  const int strow = lane >> 3;     // 0..7

  // stage chunk 0 -> buf 0
#pragma unroll
  for (int it = 0; it < 2; ++it) {
    int st = it * 8 + strow;
    bf16x8 g = *(const bf16x8*)((const __bf16*)pl + base + (size_t)st * 1024 + col8);
    float4 f0, f1;
    f0.x = (float)(__hip_bfloat16)g[0]; f0.y = (float)(__hip_bfloat16)g[1];
    f0.z = (float)(__hip_bfloat16)g[2]; f0.w = (float)(__hip_bfloat16)g[3];
    f1.x = (float)(__hip_bfloat16)g[4]; f1.y = (float)(__hip_bfloat16)g[5];
    f1.z = (float)(__hip_bfloat16)g[6]; f1.w = (float)(__hip_bfloat16)g[7];
    *(float4*)&sp[seg][0][st][col8]     = f0;
    *(float4*)&sp[seg][0][st][col8 + 4] = f1;
  }

  float S[16];
#pragma unroll
  for (int j = 0; j < 16; ++j) S[j] = 0.f;
  __syncthreads();

  for (int c = 0; c < 128; ++c) {
    const int buf = c & 1;
    bf16x8 pre[2];
    const bool hasNext = (c + 1 < 128);
    if (hasNext) {                     // issue next chunk's loads now (hidden by compute)
      int t0n = (c + 1) * 16;
#pragma unroll
      for (int it = 0; it < 2; ++it) {
        int st = it * 8 + strow;
        pre[it] = *(const bf16x8*)((const __bf16*)pl + base + (size_t)(t0n + st) * 1024 + col8);
      }
    }

#pragma unroll 2
    for (int i = 0; i < 16; ++i) {
      const float* kp = sp[1][buf][i];
      const float* qp = sp[0][buf][i];
      float kk[16], qq[16];
#pragma unroll
      for (int j = 0; j < 16; j += 4) {
        *(float4*)&kk[j] = *(const float4*)(kp + c0 + j);
        *(float4*)&qq[j] = *(const float4*)(qp + c0 + j);
      }
      float vr = sp[2][buf][i][r];
      float ar = sp[3][buf][i][r];
      float bt = sbeta[c * 16 + i];

      float d0 = 0.f, d1 = 0.f, d2 = 0.f, d3 = 0.f;
#pragma unroll
      for (int j = 0; j < 4; ++j) {
        d0 += S[j] * kk[j];       d1 += S[4 + j] * kk[4 + j];
        d2 += S[8 + j] * kk[8 + j]; d3 += S[12 + j] * kk[12 + j];
      }
      float dot = (d0 + d1) + (d2 + d3);
      dot += __shfl_xor(dot, 1);
      dot += __shfl_xor(dot, 2);
      float cc = bt * (dot - vr);          // beta * err[r]

      float o0 = 0.f, o1 = 0.f, o2 = 0.f, o3 = 0.f;
#pragma unroll
      for (int j = 0; j < 4; ++j) {
        S[j]      = ar * S[j]      - cc * kk[j];       o0 += S[j]      * qq[j];
        S[4 + j]  = ar * S[4 + j]  - cc * kk[4 + j];   o1 += S[4 + j]  * qq[4 + j];
        S[8 + j]  = ar * S[8 + j]  - cc * kk[8 + j];   o2 += S[8 + j]  * qq[8 + j];
        S[12 + j] = ar * S[12 + j] - cc * kk[12 + j];  o3 += S[12 + j] * qq[12 + j];
      }
      float od = (o0 + o1) + (o2 + o3);
      od += __shfl_xor(od, 1);
      od += __shfl_xor(od, 2);
      if ((tid & 3) == 0) o[base + (size_t)(c * 16 + i) * 1024 + r] = (bf16)od;
    }

    if (hasNext) {                      // cvt + write next chunk into buf^1
#pragma unroll
      for (int it = 0; it < 2; ++it) {
        int st = it * 8 + strow;
        bf16x8 g = pre[it];
        float4 f0, f1;
        f0.x = (float)(__hip_bfloat16)g[0]; f0.y = (float)(__hip_bfloat16)g[1];
        f0.z = (float)(__hip_bfloat16)g[2]; f0.w = (float)(__hip_bfloat16)g[3];
        f1.x = (float)(__hip_bfloat16)g[4]; f1.y = (float)(__hip_bfloat16)g[5];
        f1.z = (float)(__hip_bfloat16)g[6]; f1.w = (float)(__hip_bfloat16)g[7];
        *(float4*)&sp[seg][buf ^ 1][st][col8]     = f0;
        *(float4*)&sp[seg][buf ^ 1][st][col8 + 4] = f1;
      }
    }
    __syncthreads();
  }
}

// LayerNorm over DV=64 per (b,t,h) row, *ln_w+ln_b, *gate -> bf16
__global__ __launch_bounds__(256) void ln_gate_kernel(
    const bf16* __restrict__ o, const bf16* __restrict__ g,
    const float* __restrict__ lnw, const float* __restrict__ lnb,
    bf16* __restrict__ out)
{
  int row = blockIdx.x * 4 + (threadIdx.x >> 6);
  int lane = threadIdx.x & 63;
  size_t idx = (size_t)row * 64 + lane;
  float xv = (float)o[idx];
  float mu = xv;
#pragma unroll
  for (int s = 1; s < 64; s <<= 1) mu += __shfl_xor(mu, s);
  mu *= (1.f / 64.f);
  float d = xv - mu;
  float vv = d * d;
#pragma unroll
  for (int s = 1; s < 64; s <<= 1) vv += __shfl_xor(vv, s);
  vv *= (1.f / 64.f);
  float y = d * rsqrtf(vv + 1e-5f) * lnw[lane] + lnb[lane];
  y *= (float)g[idx];
  out[idx] = (bf16)y;
}

extern "C" void kernel_launch(void* const* d_in, const int* in_sizes, int n_in,
                              void* d_out, int out_size, void* d_ws, size_t ws_size,
                              hipStream_t stream)
{
  const float* x   = (const float*)d_in[0];
  const float* Wq  = (const float*)d_in[1];
  const float* Wk  = (const float*)d_in[2];
  const float* Wv  = (const float*)d_in[3];
  const float* Wa  = (const float*)d_in[4];
  const float* ba  = (const float*)d_in[5];
  const float* Wb  = (const float*)d_in[6];
  const float* bb  = (const float*)d_in[7];
  const float* Wg  = (const float*)d_in[8];
  const float* Wo  = (const float*)d_in[9];
  const float* qcw = (const float*)d_in[10];
  const float* qcb = (const float*)d_in[11];
  const float* kcw = (const float*)d_in[12];
  const float* kcb = (const float*)d_in[13];
  const float* vcw = (const float*)d_in[14];
  const float* vcb = (const float*)d_in[15];
  const float* lnw = (const float*)d_in[16];
  const float* lnb = (const float*)d_in[17];

  const int M = 4096, HID = 1024;
  const size_t PLANE = (size_t)M * HID;
  const size_t PB = PLANE * sizeof(bf16);          // 8 MB bf16 plane

  char* ws = (char*)d_ws;
  bf16* P  = (bf16*)(ws);            // z-plane x3, then a-gate
  bf16* qb = (bf16*)(ws + PB);       // q, then g-gate
  bf16* kb = (bf16*)(ws + 2 * PB);   // k, then normalized*gated o
  bf16* vb = (bf16*)(ws + 3 * PB);   // v, then scan output (in-place)

  // d_out as scratch until the final GEMM writes it:
  float* outf  = (float*)d_out;
  float* betab = outf;                                   // [0, 256 KB)
  bf16*  xb    = (bf16*)((char*)d_out + 8 * 1024 * 1024); // [8M, 16M)

  dim3 blk(256);
  dim3 g8(8, 32);
  int nconv = (int)(PLANE / 256);

  cvt_plane_kernel<<<(int)(PLANE / 1024), blk, 0, stream>>>(x, xb);

  gemm_bt<2><<<g8, blk, 0, stream>>>(xb, Wq, nullptr, nullptr, P, M, HID, HID);
  conv_silu_kernel<<<nconv, blk, 0, stream>>>(P, qcw, qcb, qb, 1.f);

  gemm_bt<2><<<g8, blk, 0, stream>>>(xb, Wk, nullptr, nullptr, P, M, HID, HID);
  conv_silu_kernel<<<nconv, blk, 0, stream>>>(P, kcw, kcb, kb, 0.125f);  // * DK^-0.5

  gemm_bt<2><<<g8, blk, 0, stream>>>(xb, Wv, nullptr, nullptr, P, M, HID, HID);
  conv_silu_kernel<<<nconv, blk, 0, stream>>>(P, vcw, vcb, vb, 1.f);

  gemm_bt<3><<<g8, blk, 0, stream>>>(xb, Wa, ba, nullptr, P, M, HID, HID);
  gemm_bt<1><<<dim3(1, 32), blk, 0, stream>>>(xb, Wb, bb, betab, nullptr, M, 16, HID);

  scan_kernel<<<32, blk, 0, stream>>>(qb, kb, vb, P, betab, vb);

  gemm_bt<3><<<g8, blk, 0, stream>>>(xb, Wg, nullptr, nullptr, qb, M, HID, HID);

  ln_gate_kernel<<<M * 16 / 4, blk, 0, stream>>>(vb, qb, lnw, lnb, kb);

  gemm_bt<4><<<g8, blk, 0, stream>>>(kb, Wo, nullptr, outf, nullptr, M, HID, HID);
}